// Round 11
// baseline (297.922 us; speedup 1.0000x reference)
//
#include <hip/hip_runtime.h>

#define TPB 256
static inline int cdiv(int a, int b){ return (a + b - 1) / b; }

#define EPSL 1e-6f
#define ACT_TANH 0
#define ACT_RELU 1
#define ACT_SIG  2
#define ACT_NONE 3

__device__ __forceinline__ float sigf(float x){ return 1.0f / (1.0f + __expf(-x)); }
__device__ __forceinline__ float clip01(float x){ return fminf(fmaxf(x, 0.f), 1.f); }

// ---------------- workspace layout (float offsets; ws = 256 MiB = 67.1M floats) ----------------
#define OFF_Y1   0
#define OFF_XF   1409024
#define OFF_XMIU 2111488
#define OFF_H1   2811904
#define OFF_INP  4384768
#define OFF_X1   7886848
#define OFF_TAIL 12238848
#define OFF_P2   (OFF_INP + 400000)      // 8*128*12*170 = 2088960, ends 6.87M < OFF_X1
#define OFF_GP   0                        // 8*1536*256 = 3145728 < OFF_INP
#define OFF_X2P  OFF_INP                  // 294912 (p2 starts at +400000: clear)
#define OFF_FC1H OFF_X1
#define OFF_BNP  (OFF_TAIL + 64)         // 512 doubles = 1024 floats
#define OFF_WN   (OFF_TAIL + 64 + 1024)
#define OFF_W1P  (OFF_TAIL + 64 + 1024 + 17600)
#define OFF_P1   16000000                 // 8*128*40*170 = 6963200, ends 22.97M << 67M

// ---------------- misc: softmax(52) + conv_wave(5504, vectorized) + fc1 wpad(768) ----------------
__global__ void __launch_bounds__(TPB) k_misc(const float* __restrict__ a2, const float* __restrict__ o2,
                     const float* __restrict__ aw, const float* __restrict__ ow,
                     float* __restrict__ wn,
                     const float* __restrict__ x, const float* __restrict__ ww,
                     float* __restrict__ y,
                     const float* __restrict__ w1, float* __restrict__ wp){
  int bid = blockIdx.x;
  if (bid < 52){
    const float* src; float* dst; int n;
    if (bid < 20)      { src = a2 + bid*320;      dst = wn + bid*320;              n = 320; }
    else if (bid < 40) { src = o2 + (bid-20)*320; dst = wn + 6400 + (bid-20)*320;  n = 320; }
    else if (bid < 46) { src = aw + (bid-40)*400; dst = wn + 12800 + (bid-40)*400; n = 400; }
    else               { src = ow + (bid-46)*400; dst = wn + 15200 + (bid-46)*400; n = 400; }
    __shared__ float sh[TPB];
    float m = -1e30f;
    for (int i = threadIdx.x; i < n; i += TPB) m = fmaxf(m, src[i]);
    sh[threadIdx.x] = m; __syncthreads();
    for (int off = TPB/2; off > 0; off >>= 1){
      if (threadIdx.x < off) sh[threadIdx.x] = fmaxf(sh[threadIdx.x], sh[threadIdx.x+off]);
      __syncthreads();
    }
    m = sh[0]; __syncthreads();
    float s = 0.f;
    for (int i = threadIdx.x; i < n; i += TPB) s += expf(src[i] - m);
    sh[threadIdx.x] = s; __syncthreads();
    for (int off = TPB/2; off > 0; off >>= 1){
      if (threadIdx.x < off) sh[threadIdx.x] += sh[threadIdx.x+off];
      __syncthreads();
    }
    float inv = 1.0f / sh[0];
    __syncthreads();
    for (int i = threadIdx.x; i < n; i += TPB) dst[i] = expf(src[i] - m) * inv;
  } else if (bid < 52 + 5504){
    int idx = (bid - 52)*TPB + threadIdx.x;
    int l = idx % 688; int t = idx / 688; int o = t & 15; int b = t >> 4;
    const float* xr = x + b*719 + l;
    const float* wr = ww + o*32;
    float xv[28];
    #pragma unroll
    for (int i = 0; i < 7; i++) *(float4*)&xv[4*i] = *(const float4*)(xr + 4*i);
    float s = 0.f;
    #pragma unroll
    for (int k = 0; k < 28; k++) s = fmaf(xv[k], wr[k], s);
    #pragma unroll
    for (int k = 28; k < 32; k++) s = fmaf(xr[k], wr[k], s);
    y[idx] = s;
  } else {
    int idx = (bid - 5556)*TPB + threadIdx.x;
    int k = idx % 192; int o = idx / 192;
    wp[idx] = (k < 170) ? w1[o*170 + k] : 0.f;
  }
}

// ---------------- BN stats partials: 256 blocks (16 c x 16 batch-chunks of 8) ----------------
__global__ void k_bn_part(const float* __restrict__ y, double* __restrict__ bnp){
  int c = blockIdx.x & 15, ch = blockIdx.x >> 4;
  double s = 0.0, s2 = 0.0;
  for (int i = threadIdx.x; i < 8*688; i += TPB){
    int b = ch*8 + i/688, l = i % 688;
    float v = y[(b*16 + c)*688 + l];
    s += (double)v; s2 += (double)v * (double)v;
  }
  __shared__ double sh[TPB], sh2[TPB];
  sh[threadIdx.x] = s; sh2[threadIdx.x] = s2; __syncthreads();
  for (int off = TPB/2; off > 0; off >>= 1){
    if (threadIdx.x < off){ sh[threadIdx.x] += sh[threadIdx.x+off]; sh2[threadIdx.x] += sh2[threadIdx.x+off]; }
    __syncthreads();
  }
  if (threadIdx.x == 0){ bnp[blockIdx.x] = sh[0]; bnp[256 + blockIdx.x] = sh2[0]; }
}

// ---------------- fused bn-finalize + xf + miu: y -> x_miu (128,32,171) ----------------
__global__ void k_xmiu2(const float* __restrict__ y, const double* __restrict__ bnp,
                        const float* __restrict__ g, const float* __restrict__ bb,
                        const float* __restrict__ ap, const float* __restrict__ bp,
                        const float* __restrict__ an, const float* __restrict__ bn,
                        float* __restrict__ out){
  __shared__ float smean[16], srstd[16];
  if (threadIdx.x < 16){
    int cc = threadIdx.x;
    double s = 0.0, s2 = 0.0;
    #pragma unroll
    for (int j = 0; j < 16; j++){ s += bnp[j*16 + cc]; s2 += bnp[256 + j*16 + cc]; }
    double n = 128.0*688.0;
    double m = s / n;
    double var = s2 / n - m*m;
    smean[cc] = (float)m;
    srstd[cc] = (float)(1.0 / sqrt(var + 1e-5));
  }
  __syncthreads();
  int idx = blockIdx.x*blockDim.x + threadIdx.x;
  if (idx >= 128*32*171) return;
  int l = idx % 171; int t = idx / 171; int c = t & 31; int b = t >> 5;
  int cc = c & 15;
  float mean = smean[cc], rstd = srstd[cc];
  float gc = g[cc], bc = bb[cc];
  float sign = (c < 16) ? 1.f : -1.f;
  float a  = (c < 16) ? ap[cc] : an[cc];
  float bo = (c < 16) ? bp[cc] : bn[cc];
  const float* yr = y + (b*16 + cc)*688 + 4*l;
  float v[7];
  #pragma unroll
  for (int i = 0; i < 7; i++)
    v[i] = fmaxf(fmaf(gc*(yr[i] - mean), rstd, bc), 0.f);
  float m = -1e30f;
  #pragma unroll
  for (int j = 0; j < 3; j++){
    float xf = fmaxf(fmaxf(v[2*j], v[2*j+1]), v[2*j+2]);
    m = fmaxf(m, sigf(sign * a * (xf - bo)));
  }
  out[idx] = m;
}

// ---------------- staging value generators ----------------
template<int SMODE, int LSRC, int LEFF>
__device__ __forceinline__ float stage_val(const float* __restrict__ src, int q){
  if (q < 0 || q >= LEFF) return 0.f;
  if constexpr (SMODE == 0){
    return src[q];
  } else if constexpr (SMODE == 1){
    float m = fmaxf(fmaxf(src[2*q], src[2*q+1]), src[2*q+2]);
    return tanhf(m);
  } else if constexpr (SMODE == 2){
    auto P = [&](int k){
      float m = fmaxf(fmaxf(src[2*k], src[2*k+1]), src[2*k+2]);
      return fmaxf(m, 0.f);
    };
    if (q == 0) return P(0);
    if (q == LEFF - 1) return P(LEFF/2 - 1);
    int k = q >> 1;
    return (q & 1) ? 0.75f*P(k) + 0.25f*P(k+1) : 0.25f*P(k-1) + 0.75f*P(k);
  } else {
    if (q == 0) return src[0];
    if (q == LEFF - 1) return src[LSRC - 1];
    int k = q >> 1;
    return (q & 1) ? 0.75f*src[k] + 0.25f*src[k+1] : 0.25f*src[k-1] + 0.75f*src[k];
  }
}

// ---------------- generic LDS-tiled 1D conv (kernel=3); JT positions/thread ----------------
template<int CIN, int LSRC, int LEFF, int COUT, int LOUT, int PAD, int ACT, int PL, int SMODE, int JT>
__global__ void __launch_bounds__(256) k_conv(const float* __restrict__ in,
                                              const float* __restrict__ w,
                                              const float* __restrict__ bias,
                                              float* __restrict__ outp){
  constexpr int LSEG = JT*PL;
  constexpr int WL = ((LSEG + 2) + 3) & ~3;
  constexpr int K3 = CIN*3;
  __shared__ float smem[CIN*WL + 8 + K3*COUT];
  float* sin = smem;
  float* wT  = smem + CIN*WL + 8;
  const int b = blockIdx.x;
  const int tid = threadIdx.x;
  const int base = blockIdx.y*LSEG - PAD;

  const float* gin = in + b*CIN*LSRC;
  for (int e = tid; e < CIN*WL; e += 256){
    int i = e / WL, c = e - i*WL;
    sin[e] = stage_val<SMODE, LSRC, LEFF>(gin + i*LSRC, base + c);
  }
  if (tid < 8) sin[CIN*WL + tid] = 0.f;
  for (int e = tid; e < K3*COUT; e += 256){
    int o = e & (COUT-1), m = e / COUT;
    wT[m*COUT + o] = w[o*K3 + m];
  }
  __syncthreads();

  const int to = tid / PL, tp = tid - (tid/PL)*PL;
  const int o0 = to*4;
  const int pl0 = JT*tp;
  float acc[JT][4];
  #pragma unroll
  for (int j = 0; j < JT; j++)
    #pragma unroll
    for (int oo = 0; oo < 4; oo++) acc[j][oo] = 0.f;

  for (int i = 0; i < CIN; i++){
    const float* srow = sin + i*WL + pl0;
    float xv[JT+2];
    #pragma unroll
    for (int j = 0; j < JT+2; j++) xv[j] = srow[j];
    const float* wrow = wT + (i*3)*COUT + o0;
    float wv[3][4];
    #pragma unroll
    for (int k = 0; k < 3; k++)
      *(float4*)&wv[k][0] = *(const float4*)(wrow + k*COUT);
    #pragma unroll
    for (int j = 0; j < JT; j++)
      #pragma unroll
      for (int k = 0; k < 3; k++)
        #pragma unroll
        for (int oo = 0; oo < 4; oo++)
          acc[j][oo] = fmaf(xv[j+k], wv[k][oo], acc[j][oo]);
  }

  const int pg0 = blockIdx.y*LSEG + pl0;
  float bv[4];
  #pragma unroll
  for (int oo = 0; oo < 4; oo++) bv[oo] = bias[o0 + oo];
  #pragma unroll
  for (int oo = 0; oo < 4; oo++){
    float* orow = outp + (b*COUT + o0 + oo)*LOUT;
    #pragma unroll
    for (int j = 0; j < JT; j++){
      int p = pg0 + j;
      if (p < LOUT){
        float s = acc[j][oo] + bv[oo];
        float r;
        if (ACT == ACT_TANH)      r = tanhf(s);
        else if (ACT == ACT_RELU) r = fmaxf(s, 0.f);
        else if (ACT == ACT_SIG)  r = sigf(s);
        else                      r = s;
        orow[p] = r;
      }
    }
  }
}

// ---------------- inp: maxpool4(h4) + segment masking, 4 outputs/thread ----------------
__global__ void k_inp(const float* __restrict__ h4, const float* __restrict__ xmiu,
                      float* __restrict__ inp){
  int idx = blockIdx.x*blockDim.x + threadIdx.x;
  if (idx >= 128*32*43) return;
  int lh = idx % 43; int t = idx / 43; int c = t & 31; int b = t >> 5;
  int l0 = 4*lh;
  const float* hr = h4 + t*174 + l0;
  float h[8];
  *(float4*)&h[0] = *(const float4*)hr;
  *(float4*)&h[4] = *(const float4*)(hr + 4);
  float wv[4];
  #pragma unroll
  for (int j = 0; j < 4; j++)
    wv[j] = fmaxf(fmaxf(h[j], h[j+1]), fmaxf(h[j+2], h[j+3]));
  float4 xm = *(const float4*)(xmiu + t*171 + l0);
  float pr[4] = {wv[0]*xm.x, wv[1]*xm.y, wv[2]*xm.z, wv[3]*xm.w};
  const float lo[5] = {0.0f, 0.2f, 0.4f, 0.6f, 0.8f};
  const float hi[5] = {0.2f, 0.4f, 0.6f, 0.8f, 2.0f};
  float* op = inp + (b*160 + c)*171 + l0;
  bool full = (l0 + 4 <= 171);
  #pragma unroll
  for (int s = 0; s < 5; s++){
    float4 r;
    r.x = (wv[0] >= lo[s] && wv[0] < hi[s]) ? pr[0] : 0.f;
    r.y = (wv[1] >= lo[s] && wv[1] < hi[s]) ? pr[1] : 0.f;
    r.z = (wv[2] >= lo[s] && wv[2] < hi[s]) ? pr[2] : 0.f;
    r.w = (wv[3] >= lo[s] && wv[3] < hi[s]) ? pr[3] : 0.f;
    if (full) *(float4*)(op + s*32*171) = r;
    else {
      #pragma unroll
      for (int j = 0; j < 4; j++)
        if (l0 + j < 171) op[s*32*171 + j] = ((float*)&r)[j];
    }
  }
}

// ---------------- fused logic1p (blocks 0..1359, 8 chunks) + until 4/thread vectorized ----------------
__global__ void __launch_bounds__(TPB) k_ul1(const float* __restrict__ inp, const float* __restrict__ wn,
                                             float* __restrict__ x1, float* __restrict__ p1){
  int bid = blockIdx.x;
  if (bid < 1360){                                // logic1p: (85, ch=8, v=2), heavy -> first
    int xb = bid % 85; int rr = bid / 85; int ch = rr & 7; int v = rr >> 3;
    int bl = xb*TPB + threadIdx.x;
    int l = bl % 170; int b = bl / 170;
    const float* W = wn + (v ? 6400 : 0);
    float acc[20];
    #pragma unroll
    for (int o = 0; o < 20; o++) acc[o] = 0.f;
    int c0 = ch*20;
    const float* ir = inp + (b*160 + c0)*171 + l;
    for (int c = 0; c < 20; c++){
      float2 uu = *(const float2*)ir;
      float u0 = clip01(uu.x);
      float u1 = clip01(uu.y);
      float g0, g1;
      if (v){ g0 = __logf(1.f - u0 + EPSL); g1 = __logf(1.f - u1 + EPSL); }
      else  { g0 = __logf(u0 + EPSL);       g1 = __logf(u1 + EPSL); }
      const float* wc = W + 2*(c0 + c);
      #pragma unroll
      for (int o = 0; o < 20; o++)
        acc[o] = fmaf(wc[o*320], g0, fmaf(wc[o*320 + 1], g1, acc[o]));
      ir += 171;
    }
    float* pp = p1 + ((ch*128 + b)*40 + v*20)*170 + l;
    #pragma unroll
    for (int o = 0; o < 20; o++) pp[o*170] = acc[o];
  } else {                                        // until: 4 outputs per thread, vector window
    int idx = (bid - 1360)*TPB + threadIdx.x;     // 128*160*43
    int lh = idx % 43; int t = idx / 43; int c = t % 160; int b = t / 160;
    int l0 = 4*lh;
    const float* base = inp + (b*160 + c)*171 + l0;
    float vr[29];
    #pragma unroll
    for (int i = 0; i < 7; i++) *(float4*)&vr[4*i] = *(const float4*)(base + 4*i);
    vr[28] = base[28];
    float v[29];
    #pragma unroll
    for (int i = 0; i < 29; i++) v[i] = (l0 + i < 171) ? vr[i] : 0.f;
    float rm0 = v[0], o0 = 0.f;
    float rm1 = v[1], o1 = 0.f;
    float rm2 = v[2], o2 = 0.f;
    float rm3 = v[3], o3 = 0.f;
    #pragma unroll
    for (int d = 1; d <= 25; d++){
      o0 = fmaxf(o0, fminf(rm0, v[d]));     rm0 = fminf(rm0, v[d]);
      o1 = fmaxf(o1, fminf(rm1, v[d+1]));   rm1 = fminf(rm1, v[d+1]);
      o2 = fmaxf(o2, fminf(rm2, v[d+2]));   rm2 = fminf(rm2, v[d+2]);
      o3 = fmaxf(o3, fminf(rm3, v[d+3]));   rm3 = fminf(rm3, v[d+3]);
    }
    float* xw = x1 + ((b*200) + 40 + c)*170;
    if (l0 + 1 < 170){ float2 ov = {o0, o1}; *(float2*)&xw[l0] = ov; }
    if (l0 + 3 < 170){ float2 ov = {o2, o3}; *(float2*)&xw[l0 + 2] = ov; }
  }
}

// ---------------- logic stage 2 partials: grid (85, ch=8, v=2); float2 pair loads ----------------
__global__ void __launch_bounds__(TPB) k_logic2p(const float* __restrict__ x1, const float* __restrict__ p1,
                                                 const float* __restrict__ wn, float* __restrict__ p2){
  int bl = blockIdx.x*TPB + threadIdx.x;
  int l = bl % 170; int b = bl / 170;
  int ch = blockIdx.y, v = blockIdx.z;
  const float* W = wn + 12800 + (v ? 2400 : 0);
  float acc[6] = {0.f,0.f,0.f,0.f,0.f,0.f};
  int c0 = ch*25;
  bool have0 = (l > 0);
  for (int c = c0; c < c0 + 25; c++){
    float u0 = 0.f, u1;
    if (c < 40){
      if (have0){
        float s0 = 0.f, s1 = 0.f;
        #pragma unroll
        for (int q = 0; q < 8; q++){
          float2 pv = *(const float2*)&p1[((q*128 + b)*40 + c)*170 + l - 1];
          s0 += pv.x; s1 += pv.y;
        }
        float e0 = __expf(s0), e1 = __expf(s1);
        u0 = (c < 20) ? e0 : fmaxf(0.f, 1.f - e0);
        u1 = (c < 20) ? e1 : fmaxf(0.f, 1.f - e1);
      } else {
        float s1 = 0.f;
        #pragma unroll
        for (int q = 0; q < 8; q++) s1 += p1[((q*128 + b)*40 + c)*170 + l];
        float e1 = __expf(s1);
        u1 = (c < 20) ? e1 : fmaxf(0.f, 1.f - e1);
      }
    } else {
      if (have0){
        float2 xv = *(const float2*)&x1[(b*200 + c)*170 + l - 1];
        u0 = xv.x; u1 = xv.y;
      } else {
        u1 = x1[(b*200 + c)*170 + l];
      }
    }
    float g0 = 0.f;
    if (have0){
      float uc = clip01(u0);
      g0 = v ? __logf(1.f - uc + EPSL) : __logf(uc + EPSL);
    }
    float uc1 = clip01(u1);
    float g1 = v ? __logf(1.f - uc1 + EPSL) : __logf(uc1 + EPSL);
    const float* wc = W + 2*c;
    #pragma unroll
    for (int o = 0; o < 6; o++)
      acc[o] = fmaf(wc[o*400], g0, fmaf(wc[o*400 + 1], g1, acc[o]));
  }
  float* pp = p2 + ((ch*128 + b)*12 + v*6)*170 + l;
  #pragma unroll
  for (int o = 0; o < 6; o++) pp[o*170] = acc[o];
}

// ---------------- fin2: combine 8 p2 chunks -> x2 padded to K=192 ----------------
__global__ void k_fin2(const float* __restrict__ p2, float* __restrict__ x2p){
  int idx = blockIdx.x*blockDim.x + threadIdx.x;
  if (idx >= 128*12*192) return;
  int l = idx % 192; int ro = idx / 192;
  if (l >= 170){ x2p[ro*192 + l] = 0.f; return; }
  int o = ro % 12; int b = ro / 12;
  float s = 0.f;
  #pragma unroll
  for (int ch = 0; ch < 8; ch++) s += p2[((ch*128 + b)*12 + o)*170 + l];
  float e = __expf(s);
  float r = (o < 6) ? e : fmaxf(0.f, 1.f - e);
  x2p[ro*192 + l] = r;
}

// ---------------- pipelined tiled GEMM ----------------
template<int M, int N, int K, int KSPLIT, int ACT>
__global__ void __launch_bounds__(256) k_gemm(const float* __restrict__ A,
                                              const float* __restrict__ W,
                                              const float* __restrict__ bias,
                                              float* __restrict__ C){
  static_assert(K % (KSPLIT*32) == 0, "K split");
  constexpr int KC = K / KSPLIT;
  constexpr int NT = KC / 32;
  constexpr int S = 68;
  __shared__ float As[2][32*S];
  __shared__ float Bs[2][32*S];
  const int m0 = blockIdx.x*64, n0 = blockIdx.y*64;
  const int kbeg = blockIdx.z*KC;
  const int tid = threadIdx.x;
  const int row = tid >> 2;
  const int c4  = (tid & 3)*4;
  const int tm  = (tid & 15)*4;
  const int tn  = (tid >> 4)*4;

  const float* Ar = A + (m0 + row)*K + kbeg + c4;
  const float* Wr = W + (n0 + row)*K + kbeg + c4;

  float4 ra0 = *(const float4*)(Ar);
  float4 ra1 = *(const float4*)(Ar + 16);
  float4 rb0 = *(const float4*)(Wr);
  float4 rb1 = *(const float4*)(Wr + 16);

  float acc[4][4] = {{0,0,0,0},{0,0,0,0},{0,0,0,0},{0,0,0,0}};
  int buf = 0;
  {
    float* a = As[0]; float* b = Bs[0];
    #pragma unroll
    for (int i = 0; i < 4; i++){
      a[(c4 + i)*S + row]      = ((const float*)&ra0)[i];
      a[(c4 + 16 + i)*S + row] = ((const float*)&ra1)[i];
      b[(c4 + i)*S + row]      = ((const float*)&rb0)[i];
      b[(c4 + 16 + i)*S + row] = ((const float*)&rb1)[i];
    }
  }
  __syncthreads();

  for (int t = 0; t < NT; t++){
    if (t + 1 < NT){
      Ar += 32; Wr += 32;
      ra0 = *(const float4*)(Ar);
      ra1 = *(const float4*)(Ar + 16);
      rb0 = *(const float4*)(Wr);
      rb1 = *(const float4*)(Wr + 16);
    }
    const float* a = As[buf]; const float* b = Bs[buf];
    #pragma unroll
    for (int k = 0; k < 32; k++){
      const float4 av = *(const float4*)(a + k*S + tm);
      const float4 bv = *(const float4*)(b + k*S + tn);
      acc[0][0] = fmaf(av.x, bv.x, acc[0][0]); acc[0][1] = fmaf(av.x, bv.y, acc[0][1]);
      acc[0][2] = fmaf(av.x, bv.z, acc[0][2]); acc[0][3] = fmaf(av.x, bv.w, acc[0][3]);
      acc[1][0] = fmaf(av.y, bv.x, acc[1][0]); acc[1][1] = fmaf(av.y, bv.y, acc[1][1]);
      acc[1][2] = fmaf(av.y, bv.z, acc[1][2]); acc[1][3] = fmaf(av.y, bv.w, acc[1][3]);
      acc[2][0] = fmaf(av.z, bv.x, acc[2][0]); acc[2][1] = fmaf(av.z, bv.y, acc[2][1]);
      acc[2][2] = fmaf(av.z, bv.z, acc[2][2]); acc[2][3] = fmaf(av.z, bv.w, acc[2][3]);
      acc[3][0] = fmaf(av.w, bv.x, acc[3][0]); acc[3][1] = fmaf(av.w, bv.y, acc[3][1]);
      acc[3][2] = fmaf(av.w, bv.z, acc[3][2]); acc[3][3] = fmaf(av.w, bv.w, acc[3][3]);
    }
    if (t + 1 < NT){
      int nb = buf ^ 1;
      float* an = As[nb]; float* bn = Bs[nb];
      #pragma unroll
      for (int i = 0; i < 4; i++){
        an[(c4 + i)*S + row]      = ((const float*)&ra0)[i];
        an[(c4 + 16 + i)*S + row] = ((const float*)&ra1)[i];
        bn[(c4 + i)*S + row]      = ((const float*)&rb0)[i];
        bn[(c4 + 16 + i)*S + row] = ((const float*)&rb1)[i];
      }
      __syncthreads();
      buf = nb;
    }
  }

  if (KSPLIT == 1){
    #pragma unroll
    for (int i = 0; i < 4; i++){
      float4 vv;
      vv.x = acc[i][0] + bias[n0 + tn];
      vv.y = acc[i][1] + bias[n0 + tn + 1];
      vv.z = acc[i][2] + bias[n0 + tn + 2];
      vv.w = acc[i][3] + bias[n0 + tn + 3];
      if (ACT == ACT_RELU){
        vv.x = fmaxf(vv.x, 0.f); vv.y = fmaxf(vv.y, 0.f);
        vv.z = fmaxf(vv.z, 0.f); vv.w = fmaxf(vv.w, 0.f);
      }
      *(float4*)&C[(m0 + tm + i)*N + n0 + tn] = vv;
    }
  } else {
    float* Cz = C + (size_t)blockIdx.z*M*N;
    #pragma unroll
    for (int i = 0; i < 4; i++){
      float4 vv = {acc[i][0], acc[i][1], acc[i][2], acc[i][3]};
      *(float4*)&Cz[(m0 + tm + i)*N + n0 + tn] = vv;
    }
  }
}

// ---------------- tail: fc2 combine(8) + bias + relu + fc3 -> out (1536,10) ----------------
__global__ void __launch_bounds__(256) k_tail(const float* __restrict__ gp,
                                              const float* __restrict__ b2,
                                              const float* __restrict__ w3,
                                              const float* __restrict__ b3,
                                              float* __restrict__ out){
  constexpr int MN = 1536*256;
  __shared__ float sh[256];
  __shared__ float ps[160];
  const int row = blockIdx.x;
  const int t = threadIdx.x;
  float s = b2[t];
  #pragma unroll
  for (int z = 0; z < 8; z++) s += gp[(size_t)z*MN + row*256 + t];
  sh[t] = fmaxf(s, 0.f);
  __syncthreads();
  if (t < 160){
    int q = t >> 4, j = t & 15;
    const float* wr = w3 + q*256 + j*16;
    const float* hr = sh + j*16;
    float p = 0.f;
    #pragma unroll
    for (int i = 0; i < 16; i++) p = fmaf(hr[i], wr[i], p);
    ps[t] = p;
  }
  __syncthreads();
  if (t < 10){
    float s3 = b3[t];
    #pragma unroll
    for (int j = 0; j < 16; j++) s3 += ps[t*16 + j];
    out[row*10 + t] = s3;
  }
}

extern "C" void kernel_launch(void* const* d_in, const int* in_sizes, int n_in,
                              void* d_out, int out_size, void* d_ws, size_t ws_size,
                              hipStream_t stream) {
  const float* x      = (const float*)d_in[0];
  const float* wave_w = (const float*)d_in[1];
  const float* bn_g   = (const float*)d_in[2];
  const float* bn_b   = (const float*)d_in[3];
  const float* miu_ap = (const float*)d_in[4];
  const float* miu_bp = (const float*)d_in[5];
  const float* miu_an = (const float*)d_in[6];
  const float* miu_bn = (const float*)d_in[7];
  const float* ae_w1  = (const float*)d_in[8];
  const float* ae_b1  = (const float*)d_in[9];
  const float* ae_w2  = (const float*)d_in[10];
  const float* ae_b2  = (const float*)d_in[11];
  const float* ae_w3  = (const float*)d_in[12];
  const float* ae_b3  = (const float*)d_in[13];
  const float* ae_w4  = (const float*)d_in[14];
  const float* ae_b4  = (const float*)d_in[15];
  const float* and2_w = (const float*)d_in[16];
  const float* or2_w  = (const float*)d_in[17];
  const float* and_w  = (const float*)d_in[18];
  const float* or_w   = (const float*)d_in[19];
  const float* fc1_w  = (const float*)d_in[20];
  const float* fc1_b  = (const float*)d_in[21];
  const float* fc2_w  = (const float*)d_in[22];
  const float* fc2_b  = (const float*)d_in[23];
  const float* fc3_w  = (const float*)d_in[24];
  const float* fc3_b  = (const float*)d_in[25];
  float* out = (float*)d_out;
  float* ws  = (float*)d_ws;

  float* y1    = ws + OFF_Y1;
  float* xmiu  = ws + OFF_XMIU;
  float* c1    = ws + OFF_H1;
  float* c2    = ws + OFF_XF;
  float* h3    = ws + OFF_Y1;
  float* h4    = ws + OFF_H1;
  float* inp   = ws + OFF_INP;
  float* x1    = ws + OFF_X1;
  float* p1    = ws + OFF_P1;
  float* p2    = ws + OFF_P2;
  float* gp    = ws + OFF_GP;
  float* x2p   = ws + OFF_X2P;
  float* w1p   = ws + OFF_W1P;
  float* fc1h  = ws + OFF_FC1H;
  double* bnp  = (double*)(ws + OFF_BNP);
  float* wn    = ws + OFF_WN;

  k_misc     <<<52 + 5504 + 768, TPB, 0, stream>>>(and2_w, or2_w, and_w, or_w, wn,
                                                   x, wave_w, y1, fc1_w, w1p);
  k_bn_part  <<<256, TPB, 0, stream>>>(y1, bnp);
  k_xmiu2    <<<cdiv(128*32*171, TPB), TPB, 0, stream>>>(y1, bnp, bn_g, bn_b,
                                                         miu_ap, miu_bp, miu_an, miu_bn, xmiu);

  k_conv<32,171,171,64,171,1,ACT_NONE,16,0,4><<<dim3(128,3), 256, 0, stream>>>(xmiu, ae_w1, ae_b1, c1);
  k_conv<64,171, 85,32, 85,1,ACT_NONE,32,1,2><<<dim3(128,2), 256, 0, stream>>>(c1, ae_w2, ae_b2, c2);
  k_conv<32, 85, 84,64, 86,2,ACT_TANH,16,2,4><<<dim3(128,2), 256, 0, stream>>>(c2, ae_w3, ae_b3, h3);
  k_conv<64, 86,172,32,174,2,ACT_SIG ,32,3,2><<<dim3(128,3), 256, 0, stream>>>(h3, ae_w4, ae_b4, h4);

  k_inp      <<<cdiv(128*32*43, TPB), TPB, 0, stream>>>(h4, xmiu, inp);
  k_ul1      <<<1360 + 3440, TPB, 0, stream>>>(inp, wn, x1, p1);
  k_logic2p  <<<dim3(85, 8, 2), TPB, 0, stream>>>(x1, p1, wn, p2);
  k_fin2     <<<cdiv(128*12*192, TPB), TPB, 0, stream>>>(p2, x2p);

  k_gemm<1536,1024,192,1,ACT_RELU><<<dim3(24,16,1), 256, 0, stream>>>(x2p, w1p, fc1_b, fc1h);
  k_gemm<1536,256,1024,8,ACT_NONE><<<dim3(24,4,8), 256, 0, stream>>>(fc1h, fc2_w, fc2_b, gp);
  k_tail     <<<1536, 256, 0, stream>>>(gp, fc2_b, fc3_w, fc3_b, out);
}

// Round 12
// 295.300 us; speedup vs baseline: 1.0089x; 1.0089x over previous
//
#include <hip/hip_runtime.h>

#define TPB 256
static inline int cdiv(int a, int b){ return (a + b - 1) / b; }

#define EPSL 1e-6f
#define ACT_TANH 0
#define ACT_RELU 1
#define ACT_SIG  2
#define ACT_NONE 3

__device__ __forceinline__ float sigf(float x){ return 1.0f / (1.0f + __expf(-x)); }
__device__ __forceinline__ float clip01(float x){ return fminf(fmaxf(x, 0.f), 1.f); }

// ---------------- workspace layout (float offsets; ws = 256 MiB = 67.1M floats) ----------------
#define OFF_Y1   0
#define OFF_XF   1409024
#define OFF_XMIU 2111488
#define OFF_H1   2811904
#define OFF_INP  4384768
#define OFF_X1   7886848
#define OFF_TAIL 12238848
#define OFF_P2   (OFF_INP + 400000)      // 8*128*12*170 = 2088960, ends 6.87M < OFF_X1
#define OFF_GP   0                        // 8*1536*256 = 3145728 < OFF_INP
#define OFF_X2P  OFF_INP                  // 294912 (p2 starts at +400000: clear)
#define OFF_FC1H OFF_X1
#define OFF_BNP  (OFF_TAIL + 64)         // 512 doubles = 1024 floats
#define OFF_WN   (OFF_TAIL + 64 + 1024)
#define OFF_W1P  (OFF_TAIL + 64 + 1024 + 17600)
#define OFF_P1   16000000                 // 8*128*40*170 = 6963200, ends 22.97M << 67M

// ---------------- misc: softmax(52) + conv_wave(5504, vectorized) + fc1 wpad(768) ----------------
__global__ void __launch_bounds__(TPB) k_misc(const float* __restrict__ a2, const float* __restrict__ o2,
                     const float* __restrict__ aw, const float* __restrict__ ow,
                     float* __restrict__ wn,
                     const float* __restrict__ x, const float* __restrict__ ww,
                     float* __restrict__ y,
                     const float* __restrict__ w1, float* __restrict__ wp){
  int bid = blockIdx.x;
  if (bid < 52){
    const float* src; float* dst; int n;
    if (bid < 20)      { src = a2 + bid*320;      dst = wn + bid*320;              n = 320; }
    else if (bid < 40) { src = o2 + (bid-20)*320; dst = wn + 6400 + (bid-20)*320;  n = 320; }
    else if (bid < 46) { src = aw + (bid-40)*400; dst = wn + 12800 + (bid-40)*400; n = 400; }
    else               { src = ow + (bid-46)*400; dst = wn + 15200 + (bid-46)*400; n = 400; }
    __shared__ float sh[TPB];
    float m = -1e30f;
    for (int i = threadIdx.x; i < n; i += TPB) m = fmaxf(m, src[i]);
    sh[threadIdx.x] = m; __syncthreads();
    for (int off = TPB/2; off > 0; off >>= 1){
      if (threadIdx.x < off) sh[threadIdx.x] = fmaxf(sh[threadIdx.x], sh[threadIdx.x+off]);
      __syncthreads();
    }
    m = sh[0]; __syncthreads();
    float s = 0.f;
    for (int i = threadIdx.x; i < n; i += TPB) s += expf(src[i] - m);
    sh[threadIdx.x] = s; __syncthreads();
    for (int off = TPB/2; off > 0; off >>= 1){
      if (threadIdx.x < off) sh[threadIdx.x] += sh[threadIdx.x+off];
      __syncthreads();
    }
    float inv = 1.0f / sh[0];
    __syncthreads();
    for (int i = threadIdx.x; i < n; i += TPB) dst[i] = expf(src[i] - m) * inv;
  } else if (bid < 52 + 5504){
    int idx = (bid - 52)*TPB + threadIdx.x;
    int l = idx % 688; int t = idx / 688; int o = t & 15; int b = t >> 4;
    const float* xr = x + b*719 + l;
    const float* wr = ww + o*32;
    float xv[28];
    #pragma unroll
    for (int i = 0; i < 7; i++) *(float4*)&xv[4*i] = *(const float4*)(xr + 4*i);
    float s = 0.f;
    #pragma unroll
    for (int k = 0; k < 28; k++) s = fmaf(xv[k], wr[k], s);
    #pragma unroll
    for (int k = 28; k < 32; k++) s = fmaf(xr[k], wr[k], s);
    y[idx] = s;
  } else {
    int idx = (bid - 5556)*TPB + threadIdx.x;
    int k = idx % 192; int o = idx / 192;
    wp[idx] = (k < 170) ? w1[o*170 + k] : 0.f;
  }
}

// ---------------- BN stats partials: 256 blocks (16 c x 16 batch-chunks of 8) ----------------
__global__ void k_bn_part(const float* __restrict__ y, double* __restrict__ bnp){
  int c = blockIdx.x & 15, ch = blockIdx.x >> 4;
  double s = 0.0, s2 = 0.0;
  for (int i = threadIdx.x; i < 8*688; i += TPB){
    int b = ch*8 + i/688, l = i % 688;
    float v = y[(b*16 + c)*688 + l];
    s += (double)v; s2 += (double)v * (double)v;
  }
  __shared__ double sh[TPB], sh2[TPB];
  sh[threadIdx.x] = s; sh2[threadIdx.x] = s2; __syncthreads();
  for (int off = TPB/2; off > 0; off >>= 1){
    if (threadIdx.x < off){ sh[threadIdx.x] += sh[threadIdx.x+off]; sh2[threadIdx.x] += sh2[threadIdx.x+off]; }
    __syncthreads();
  }
  if (threadIdx.x == 0){ bnp[blockIdx.x] = sh[0]; bnp[256 + blockIdx.x] = sh2[0]; }
}

// ---------------- fused bn-finalize + xf + miu: y -> x_miu (128,32,171) ----------------
__global__ void k_xmiu2(const float* __restrict__ y, const double* __restrict__ bnp,
                        const float* __restrict__ g, const float* __restrict__ bb,
                        const float* __restrict__ ap, const float* __restrict__ bp,
                        const float* __restrict__ an, const float* __restrict__ bn,
                        float* __restrict__ out){
  __shared__ float smean[16], srstd[16];
  if (threadIdx.x < 16){
    int cc = threadIdx.x;
    double s = 0.0, s2 = 0.0;
    #pragma unroll
    for (int j = 0; j < 16; j++){ s += bnp[j*16 + cc]; s2 += bnp[256 + j*16 + cc]; }
    double n = 128.0*688.0;
    double m = s / n;
    double var = s2 / n - m*m;
    smean[cc] = (float)m;
    srstd[cc] = (float)(1.0 / sqrt(var + 1e-5));
  }
  __syncthreads();
  int idx = blockIdx.x*blockDim.x + threadIdx.x;
  if (idx >= 128*32*171) return;
  int l = idx % 171; int t = idx / 171; int c = t & 31; int b = t >> 5;
  int cc = c & 15;
  float mean = smean[cc], rstd = srstd[cc];
  float gc = g[cc], bc = bb[cc];
  float sign = (c < 16) ? 1.f : -1.f;
  float a  = (c < 16) ? ap[cc] : an[cc];
  float bo = (c < 16) ? bp[cc] : bn[cc];
  const float* yr = y + (b*16 + cc)*688 + 4*l;
  float v[7];
  #pragma unroll
  for (int i = 0; i < 7; i++)
    v[i] = fmaxf(fmaf(gc*(yr[i] - mean), rstd, bc), 0.f);
  float m = -1e30f;
  #pragma unroll
  for (int j = 0; j < 3; j++){
    float xf = fmaxf(fmaxf(v[2*j], v[2*j+1]), v[2*j+2]);
    m = fmaxf(m, sigf(sign * a * (xf - bo)));
  }
  out[idx] = m;
}

// ---------------- staging value generators ----------------
template<int SMODE, int LSRC, int LEFF>
__device__ __forceinline__ float stage_val(const float* __restrict__ src, int q){
  if (q < 0 || q >= LEFF) return 0.f;
  if constexpr (SMODE == 0){
    return src[q];
  } else if constexpr (SMODE == 1){
    float m = fmaxf(fmaxf(src[2*q], src[2*q+1]), src[2*q+2]);
    return tanhf(m);
  } else if constexpr (SMODE == 2){
    auto P = [&](int k){
      float m = fmaxf(fmaxf(src[2*k], src[2*k+1]), src[2*k+2]);
      return fmaxf(m, 0.f);
    };
    if (q == 0) return P(0);
    if (q == LEFF - 1) return P(LEFF/2 - 1);
    int k = q >> 1;
    return (q & 1) ? 0.75f*P(k) + 0.25f*P(k+1) : 0.25f*P(k-1) + 0.75f*P(k);
  } else {
    if (q == 0) return src[0];
    if (q == LEFF - 1) return src[LSRC - 1];
    int k = q >> 1;
    return (q & 1) ? 0.75f*src[k] + 0.25f*src[k+1] : 0.25f*src[k-1] + 0.75f*src[k];
  }
}

// ---------------- generic LDS-tiled 1D conv (kernel=3); JT positions/thread ----------------
template<int CIN, int LSRC, int LEFF, int COUT, int LOUT, int PAD, int ACT, int PL, int SMODE, int JT>
__global__ void __launch_bounds__(256) k_conv(const float* __restrict__ in,
                                              const float* __restrict__ w,
                                              const float* __restrict__ bias,
                                              float* __restrict__ outp){
  constexpr int LSEG = JT*PL;
  constexpr int WL = ((LSEG + 2) + 3) & ~3;
  constexpr int K3 = CIN*3;
  __shared__ float smem[CIN*WL + 8 + K3*COUT];
  float* sin = smem;
  float* wT  = smem + CIN*WL + 8;
  const int b = blockIdx.x;
  const int tid = threadIdx.x;
  const int base = blockIdx.y*LSEG - PAD;

  const float* gin = in + b*CIN*LSRC;
  for (int e = tid; e < CIN*WL; e += 256){
    int i = e / WL, c = e - i*WL;
    sin[e] = stage_val<SMODE, LSRC, LEFF>(gin + i*LSRC, base + c);
  }
  if (tid < 8) sin[CIN*WL + tid] = 0.f;
  for (int e = tid; e < K3*COUT; e += 256){
    int o = e & (COUT-1), m = e / COUT;
    wT[m*COUT + o] = w[o*K3 + m];
  }
  __syncthreads();

  const int to = tid / PL, tp = tid - (tid/PL)*PL;
  const int o0 = to*4;
  const int pl0 = JT*tp;
  float acc[JT][4];
  #pragma unroll
  for (int j = 0; j < JT; j++)
    #pragma unroll
    for (int oo = 0; oo < 4; oo++) acc[j][oo] = 0.f;

  for (int i = 0; i < CIN; i++){
    const float* srow = sin + i*WL + pl0;
    float xv[JT+2];
    #pragma unroll
    for (int j = 0; j < JT+2; j++) xv[j] = srow[j];
    const float* wrow = wT + (i*3)*COUT + o0;
    float wv[3][4];
    #pragma unroll
    for (int k = 0; k < 3; k++)
      *(float4*)&wv[k][0] = *(const float4*)(wrow + k*COUT);
    #pragma unroll
    for (int j = 0; j < JT; j++)
      #pragma unroll
      for (int k = 0; k < 3; k++)
        #pragma unroll
        for (int oo = 0; oo < 4; oo++)
          acc[j][oo] = fmaf(xv[j+k], wv[k][oo], acc[j][oo]);
  }

  const int pg0 = blockIdx.y*LSEG + pl0;
  float bv[4];
  #pragma unroll
  for (int oo = 0; oo < 4; oo++) bv[oo] = bias[o0 + oo];
  #pragma unroll
  for (int oo = 0; oo < 4; oo++){
    float* orow = outp + (b*COUT + o0 + oo)*LOUT;
    #pragma unroll
    for (int j = 0; j < JT; j++){
      int p = pg0 + j;
      if (p < LOUT){
        float s = acc[j][oo] + bv[oo];
        float r;
        if (ACT == ACT_TANH)      r = tanhf(s);
        else if (ACT == ACT_RELU) r = fmaxf(s, 0.f);
        else if (ACT == ACT_SIG)  r = sigf(s);
        else                      r = s;
        orow[p] = r;
      }
    }
  }
}

// ---------------- conv4 + pool4 + segment masking fused: h3 -> inp (128,160,171) ----------------
// CIN=64, input h3 (LSRC=86) upsampled to LEFF=172, conv pad 2, COUT=32, sigmoid.
// Block (b, seg of 64 inp positions). sh4 holds sigmoid(conv) for 67 positions (64 + 3 pool halo).
__global__ void __launch_bounds__(256) k_conv4i(const float* __restrict__ in,
                                                const float* __restrict__ w,
                                                const float* __restrict__ bias,
                                                const float* __restrict__ xmiu,
                                                float* __restrict__ inp){
  constexpr int WL = 72;                           // staged width (need 69 cols)
  __shared__ float sin_[64*WL + 8];
  __shared__ float wT[192*32];
  __shared__ float sh4[32][68];
  const int b = blockIdx.x;
  const int base = blockIdx.y*64;                  // inp position base
  const int sbase = base - 2;                      // staged col0 -> upsampled index
  const int tid = threadIdx.x;

  const float* gin = in + b*64*86;
  for (int e = tid; e < 64*WL; e += 256){
    int i = e / WL, c = e - i*WL;
    sin_[e] = (c < 69) ? stage_val<3,86,172>(gin + i*86, sbase + c) : 0.f;
  }
  if (tid < 8) sin_[64*WL + tid] = 0.f;
  for (int e = tid; e < 192*32; e += 256){
    int o = e & 31, m = e >> 5;
    wT[m*32 + o] = w[o*192 + m];
  }
  __syncthreads();

  // main tile: 8 o-groups x 32 p-threads, JT=2 positions
  const int to = tid >> 5, tp = tid & 31;
  const int o0 = 4*to, pl0 = 2*tp;
  float acc[2][4] = {{0,0,0,0},{0,0,0,0}};
  for (int i = 0; i < 64; i++){
    const float* srow = sin_ + i*WL + pl0;
    float xv[4];
    #pragma unroll
    for (int j = 0; j < 4; j++) xv[j] = srow[j];
    const float* wrow = wT + (i*3)*32 + o0;
    float wv[3][4];
    #pragma unroll
    for (int k = 0; k < 3; k++)
      *(float4*)&wv[k][0] = *(const float4*)(wrow + k*32);
    #pragma unroll
    for (int j = 0; j < 2; j++)
      #pragma unroll
      for (int k = 0; k < 3; k++)
        #pragma unroll
        for (int oo = 0; oo < 4; oo++)
          acc[j][oo] = fmaf(xv[j+k], wv[k][oo], acc[j][oo]);
  }
  #pragma unroll
  for (int oo = 0; oo < 4; oo++){
    float bvv = bias[o0 + oo];
    #pragma unroll
    for (int j = 0; j < 2; j++)
      sh4[o0 + oo][pl0 + j] = sigf(acc[j][oo] + bvv);
  }
  // halo: positions 64..66, all 32 channels (96 threads)
  if (tid < 96){
    int hp = tid % 3, ch = tid / 3;
    float s = bias[ch];
    for (int i = 0; i < 64; i++){
      const float* sr = sin_ + i*WL + 64 + hp;
      const float* wr = wT + (i*3)*32 + ch;
      s = fmaf(sr[0], wr[0], s);
      s = fmaf(sr[1], wr[32], s);
      s = fmaf(sr[2], wr[64], s);
    }
    sh4[ch][64 + hp] = sigf(s);
  }
  __syncthreads();

  // epilogue: pool4 + 5-segment masking -> inp
  const float lo[5] = {0.0f, 0.2f, 0.4f, 0.6f, 0.8f};
  const float hi[5] = {0.2f, 0.4f, 0.6f, 0.8f, 2.0f};
  #pragma unroll
  for (int oo = 0; oo < 4; oo++){
    int ch = o0 + oo;
    const float* xmr = xmiu + (b*32 + ch)*171;
    float* op = inp + (b*160 + ch)*171;
    #pragma unroll
    for (int j = 0; j < 2; j++){
      int p = base + pl0 + j;
      if (p < 171){
        int pr = pl0 + j;
        float wv = fmaxf(fmaxf(sh4[ch][pr], sh4[ch][pr+1]),
                         fmaxf(sh4[ch][pr+2], sh4[ch][pr+3]));
        float prod = wv * xmr[p];
        #pragma unroll
        for (int s = 0; s < 5; s++){
          bool m = (wv >= lo[s]) && (wv < hi[s]);
          op[s*32*171 + p] = m ? prod : 0.f;
        }
      }
    }
  }
}

// ---------------- fused logic1p (blocks 0..1359, 8 chunks) + until 4/thread vectorized ----------------
__global__ void __launch_bounds__(TPB) k_ul1(const float* __restrict__ inp, const float* __restrict__ wn,
                                             float* __restrict__ x1, float* __restrict__ p1){
  int bid = blockIdx.x;
  if (bid < 1360){                                // logic1p: (85, ch=8, v=2), heavy -> first
    int xb = bid % 85; int rr = bid / 85; int ch = rr & 7; int v = rr >> 3;
    int bl = xb*TPB + threadIdx.x;
    int l = bl % 170; int b = bl / 170;
    const float* W = wn + (v ? 6400 : 0);
    float acc[20];
    #pragma unroll
    for (int o = 0; o < 20; o++) acc[o] = 0.f;
    int c0 = ch*20;
    const float* ir = inp + (b*160 + c0)*171 + l;
    for (int c = 0; c < 20; c++){
      float2 uu = *(const float2*)ir;
      float u0 = clip01(uu.x);
      float u1 = clip01(uu.y);
      float g0, g1;
      if (v){ g0 = __logf(1.f - u0 + EPSL); g1 = __logf(1.f - u1 + EPSL); }
      else  { g0 = __logf(u0 + EPSL);       g1 = __logf(u1 + EPSL); }
      const float* wc = W + 2*(c0 + c);
      #pragma unroll
      for (int o = 0; o < 20; o++)
        acc[o] = fmaf(wc[o*320], g0, fmaf(wc[o*320 + 1], g1, acc[o]));
      ir += 171;
    }
    float* pp = p1 + ((ch*128 + b)*40 + v*20)*170 + l;
    #pragma unroll
    for (int o = 0; o < 20; o++) pp[o*170] = acc[o];
  } else {                                        // until: 4 outputs per thread, vector window
    int idx = (bid - 1360)*TPB + threadIdx.x;     // 128*160*43
    int lh = idx % 43; int t = idx / 43; int c = t % 160; int b = t / 160;
    int l0 = 4*lh;
    const float* base = inp + (b*160 + c)*171 + l0;
    float vr[29];
    #pragma unroll
    for (int i = 0; i < 7; i++) *(float4*)&vr[4*i] = *(const float4*)(base + 4*i);
    vr[28] = base[28];
    float v[29];
    #pragma unroll
    for (int i = 0; i < 29; i++) v[i] = (l0 + i < 171) ? vr[i] : 0.f;
    float rm0 = v[0], o0 = 0.f;
    float rm1 = v[1], o1 = 0.f;
    float rm2 = v[2], o2 = 0.f;
    float rm3 = v[3], o3 = 0.f;
    #pragma unroll
    for (int d = 1; d <= 25; d++){
      o0 = fmaxf(o0, fminf(rm0, v[d]));     rm0 = fminf(rm0, v[d]);
      o1 = fmaxf(o1, fminf(rm1, v[d+1]));   rm1 = fminf(rm1, v[d+1]);
      o2 = fmaxf(o2, fminf(rm2, v[d+2]));   rm2 = fminf(rm2, v[d+2]);
      o3 = fmaxf(o3, fminf(rm3, v[d+3]));   rm3 = fminf(rm3, v[d+3]);
    }
    float* xw = x1 + ((b*200) + 40 + c)*170;
    if (l0 + 1 < 170){ float2 ov = {o0, o1}; *(float2*)&xw[l0] = ov; }
    if (l0 + 3 < 170){ float2 ov = {o2, o3}; *(float2*)&xw[l0 + 2] = ov; }
  }
}

// ---------------- logic stage 2 partials: grid (85, ch=8, v=2); float2 pair loads ----------------
__global__ void __launch_bounds__(TPB) k_logic2p(const float* __restrict__ x1, const float* __restrict__ p1,
                                                 const float* __restrict__ wn, float* __restrict__ p2){
  int bl = blockIdx.x*TPB + threadIdx.x;
  int l = bl % 170; int b = bl / 170;
  int ch = blockIdx.y, v = blockIdx.z;
  const float* W = wn + 12800 + (v ? 2400 : 0);
  float acc[6] = {0.f,0.f,0.f,0.f,0.f,0.f};
  int c0 = ch*25;
  bool have0 = (l > 0);
  for (int c = c0; c < c0 + 25; c++){
    float u0 = 0.f, u1;
    if (c < 40){
      if (have0){
        float s0 = 0.f, s1 = 0.f;
        #pragma unroll
        for (int q = 0; q < 8; q++){
          float2 pv = *(const float2*)&p1[((q*128 + b)*40 + c)*170 + l - 1];
          s0 += pv.x; s1 += pv.y;
        }
        float e0 = __expf(s0), e1 = __expf(s1);
        u0 = (c < 20) ? e0 : fmaxf(0.f, 1.f - e0);
        u1 = (c < 20) ? e1 : fmaxf(0.f, 1.f - e1);
      } else {
        float s1 = 0.f;
        #pragma unroll
        for (int q = 0; q < 8; q++) s1 += p1[((q*128 + b)*40 + c)*170 + l];
        float e1 = __expf(s1);
        u1 = (c < 20) ? e1 : fmaxf(0.f, 1.f - e1);
      }
    } else {
      if (have0){
        float2 xv = *(const float2*)&x1[(b*200 + c)*170 + l - 1];
        u0 = xv.x; u1 = xv.y;
      } else {
        u1 = x1[(b*200 + c)*170 + l];
      }
    }
    float g0 = 0.f;
    if (have0){
      float uc = clip01(u0);
      g0 = v ? __logf(1.f - uc + EPSL) : __logf(uc + EPSL);
    }
    float uc1 = clip01(u1);
    float g1 = v ? __logf(1.f - uc1 + EPSL) : __logf(uc1 + EPSL);
    const float* wc = W + 2*c;
    #pragma unroll
    for (int o = 0; o < 6; o++)
      acc[o] = fmaf(wc[o*400], g0, fmaf(wc[o*400 + 1], g1, acc[o]));
  }
  float* pp = p2 + ((ch*128 + b)*12 + v*6)*170 + l;
  #pragma unroll
  for (int o = 0; o < 6; o++) pp[o*170] = acc[o];
}

// ---------------- fin2: combine 8 p2 chunks -> x2 padded to K=192 ----------------
__global__ void k_fin2(const float* __restrict__ p2, float* __restrict__ x2p){
  int idx = blockIdx.x*blockDim.x + threadIdx.x;
  if (idx >= 128*12*192) return;
  int l = idx % 192; int ro = idx / 192;
  if (l >= 170){ x2p[ro*192 + l] = 0.f; return; }
  int o = ro % 12; int b = ro / 12;
  float s = 0.f;
  #pragma unroll
  for (int ch = 0; ch < 8; ch++) s += p2[((ch*128 + b)*12 + o)*170 + l];
  float e = __expf(s);
  float r = (o < 6) ? e : fmaxf(0.f, 1.f - e);
  x2p[ro*192 + l] = r;
}

// ---------------- pipelined tiled GEMM ----------------
template<int M, int N, int K, int KSPLIT, int ACT>
__global__ void __launch_bounds__(256) k_gemm(const float* __restrict__ A,
                                              const float* __restrict__ W,
                                              const float* __restrict__ bias,
                                              float* __restrict__ C){
  static_assert(K % (KSPLIT*32) == 0, "K split");
  constexpr int KC = K / KSPLIT;
  constexpr int NT = KC / 32;
  constexpr int S = 68;
  __shared__ float As[2][32*S];
  __shared__ float Bs[2][32*S];
  const int m0 = blockIdx.x*64, n0 = blockIdx.y*64;
  const int kbeg = blockIdx.z*KC;
  const int tid = threadIdx.x;
  const int row = tid >> 2;
  const int c4  = (tid & 3)*4;
  const int tm  = (tid & 15)*4;
  const int tn  = (tid >> 4)*4;

  const float* Ar = A + (m0 + row)*K + kbeg + c4;
  const float* Wr = W + (n0 + row)*K + kbeg + c4;

  float4 ra0 = *(const float4*)(Ar);
  float4 ra1 = *(const float4*)(Ar + 16);
  float4 rb0 = *(const float4*)(Wr);
  float4 rb1 = *(const float4*)(Wr + 16);

  float acc[4][4] = {{0,0,0,0},{0,0,0,0},{0,0,0,0},{0,0,0,0}};
  int buf = 0;
  {
    float* a = As[0]; float* b = Bs[0];
    #pragma unroll
    for (int i = 0; i < 4; i++){
      a[(c4 + i)*S + row]      = ((const float*)&ra0)[i];
      a[(c4 + 16 + i)*S + row] = ((const float*)&ra1)[i];
      b[(c4 + i)*S + row]      = ((const float*)&rb0)[i];
      b[(c4 + 16 + i)*S + row] = ((const float*)&rb1)[i];
    }
  }
  __syncthreads();

  for (int t = 0; t < NT; t++){
    if (t + 1 < NT){
      Ar += 32; Wr += 32;
      ra0 = *(const float4*)(Ar);
      ra1 = *(const float4*)(Ar + 16);
      rb0 = *(const float4*)(Wr);
      rb1 = *(const float4*)(Wr + 16);
    }
    const float* a = As[buf]; const float* b = Bs[buf];
    #pragma unroll
    for (int k = 0; k < 32; k++){
      const float4 av = *(const float4*)(a + k*S + tm);
      const float4 bv = *(const float4*)(b + k*S + tn);
      acc[0][0] = fmaf(av.x, bv.x, acc[0][0]); acc[0][1] = fmaf(av.x, bv.y, acc[0][1]);
      acc[0][2] = fmaf(av.x, bv.z, acc[0][2]); acc[0][3] = fmaf(av.x, bv.w, acc[0][3]);
      acc[1][0] = fmaf(av.y, bv.x, acc[1][0]); acc[1][1] = fmaf(av.y, bv.y, acc[1][1]);
      acc[1][2] = fmaf(av.y, bv.z, acc[1][2]); acc[1][3] = fmaf(av.y, bv.w, acc[1][3]);
      acc[2][0] = fmaf(av.z, bv.x, acc[2][0]); acc[2][1] = fmaf(av.z, bv.y, acc[2][1]);
      acc[2][2] = fmaf(av.z, bv.z, acc[2][2]); acc[2][3] = fmaf(av.z, bv.w, acc[2][3]);
      acc[3][0] = fmaf(av.w, bv.x, acc[3][0]); acc[3][1] = fmaf(av.w, bv.y, acc[3][1]);
      acc[3][2] = fmaf(av.w, bv.z, acc[3][2]); acc[3][3] = fmaf(av.w, bv.w, acc[3][3]);
    }
    if (t + 1 < NT){
      int nb = buf ^ 1;
      float* an = As[nb]; float* bn = Bs[nb];
      #pragma unroll
      for (int i = 0; i < 4; i++){
        an[(c4 + i)*S + row]      = ((const float*)&ra0)[i];
        an[(c4 + 16 + i)*S + row] = ((const float*)&ra1)[i];
        bn[(c4 + i)*S + row]      = ((const float*)&rb0)[i];
        bn[(c4 + 16 + i)*S + row] = ((const float*)&rb1)[i];
      }
      __syncthreads();
      buf = nb;
    }
  }

  if (KSPLIT == 1){
    #pragma unroll
    for (int i = 0; i < 4; i++){
      float4 vv;
      vv.x = acc[i][0] + bias[n0 + tn];
      vv.y = acc[i][1] + bias[n0 + tn + 1];
      vv.z = acc[i][2] + bias[n0 + tn + 2];
      vv.w = acc[i][3] + bias[n0 + tn + 3];
      if (ACT == ACT_RELU){
        vv.x = fmaxf(vv.x, 0.f); vv.y = fmaxf(vv.y, 0.f);
        vv.z = fmaxf(vv.z, 0.f); vv.w = fmaxf(vv.w, 0.f);
      }
      *(float4*)&C[(m0 + tm + i)*N + n0 + tn] = vv;
    }
  } else {
    float* Cz = C + (size_t)blockIdx.z*M*N;
    #pragma unroll
    for (int i = 0; i < 4; i++){
      float4 vv = {acc[i][0], acc[i][1], acc[i][2], acc[i][3]};
      *(float4*)&Cz[(m0 + tm + i)*N + n0 + tn] = vv;
    }
  }
}

// ---------------- tail: fc2 combine(8) + bias + relu + fc3 -> out (1536,10) ----------------
__global__ void __launch_bounds__(256) k_tail(const float* __restrict__ gp,
                                              const float* __restrict__ b2,
                                              const float* __restrict__ w3,
                                              const float* __restrict__ b3,
                                              float* __restrict__ out){
  constexpr int MN = 1536*256;
  __shared__ float sh[256];
  __shared__ float ps[160];
  const int row = blockIdx.x;
  const int t = threadIdx.x;
  float s = b2[t];
  #pragma unroll
  for (int z = 0; z < 8; z++) s += gp[(size_t)z*MN + row*256 + t];
  sh[t] = fmaxf(s, 0.f);
  __syncthreads();
  if (t < 160){
    int q = t >> 4, j = t & 15;
    const float* wr = w3 + q*256 + j*16;
    const float* hr = sh + j*16;
    float p = 0.f;
    #pragma unroll
    for (int i = 0; i < 16; i++) p = fmaf(hr[i], wr[i], p);
    ps[t] = p;
  }
  __syncthreads();
  if (t < 10){
    float s3 = b3[t];
    #pragma unroll
    for (int j = 0; j < 16; j++) s3 += ps[t*16 + j];
    out[row*10 + t] = s3;
  }
}

extern "C" void kernel_launch(void* const* d_in, const int* in_sizes, int n_in,
                              void* d_out, int out_size, void* d_ws, size_t ws_size,
                              hipStream_t stream) {
  const float* x      = (const float*)d_in[0];
  const float* wave_w = (const float*)d_in[1];
  const float* bn_g   = (const float*)d_in[2];
  const float* bn_b   = (const float*)d_in[3];
  const float* miu_ap = (const float*)d_in[4];
  const float* miu_bp = (const float*)d_in[5];
  const float* miu_an = (const float*)d_in[6];
  const float* miu_bn = (const float*)d_in[7];
  const float* ae_w1  = (const float*)d_in[8];
  const float* ae_b1  = (const float*)d_in[9];
  const float* ae_w2  = (const float*)d_in[10];
  const float* ae_b2  = (const float*)d_in[11];
  const float* ae_w3  = (const float*)d_in[12];
  const float* ae_b3  = (const float*)d_in[13];
  const float* ae_w4  = (const float*)d_in[14];
  const float* ae_b4  = (const float*)d_in[15];
  const float* and2_w = (const float*)d_in[16];
  const float* or2_w  = (const float*)d_in[17];
  const float* and_w  = (const float*)d_in[18];
  const float* or_w   = (const float*)d_in[19];
  const float* fc1_w  = (const float*)d_in[20];
  const float* fc1_b  = (const float*)d_in[21];
  const float* fc2_w  = (const float*)d_in[22];
  const float* fc2_b  = (const float*)d_in[23];
  const float* fc3_w  = (const float*)d_in[24];
  const float* fc3_b  = (const float*)d_in[25];
  float* out = (float*)d_out;
  float* ws  = (float*)d_ws;

  float* y1    = ws + OFF_Y1;
  float* xmiu  = ws + OFF_XMIU;
  float* c1    = ws + OFF_H1;
  float* c2    = ws + OFF_XF;
  float* h3    = ws + OFF_Y1;
  float* inp   = ws + OFF_INP;
  float* x1    = ws + OFF_X1;
  float* p1    = ws + OFF_P1;
  float* p2    = ws + OFF_P2;
  float* gp    = ws + OFF_GP;
  float* x2p   = ws + OFF_X2P;
  float* w1p   = ws + OFF_W1P;
  float* fc1h  = ws + OFF_FC1H;
  double* bnp  = (double*)(ws + OFF_BNP);
  float* wn    = ws + OFF_WN;

  k_misc     <<<52 + 5504 + 768, TPB, 0, stream>>>(and2_w, or2_w, and_w, or_w, wn,
                                                   x, wave_w, y1, fc1_w, w1p);
  k_bn_part  <<<256, TPB, 0, stream>>>(y1, bnp);
  k_xmiu2    <<<cdiv(128*32*171, TPB), TPB, 0, stream>>>(y1, bnp, bn_g, bn_b,
                                                         miu_ap, miu_bp, miu_an, miu_bn, xmiu);

  k_conv<32,171,171,64,171,1,ACT_NONE,16,0,4><<<dim3(128,3), 256, 0, stream>>>(xmiu, ae_w1, ae_b1, c1);
  k_conv<64,171, 85,32, 85,1,ACT_NONE,32,1,2><<<dim3(128,2), 256, 0, stream>>>(c1, ae_w2, ae_b2, c2);
  k_conv<32, 85, 84,64, 86,2,ACT_TANH,16,2,4><<<dim3(128,2), 256, 0, stream>>>(c2, ae_w3, ae_b3, h3);
  k_conv4i   <<<dim3(128,3), 256, 0, stream>>>(h3, ae_w4, ae_b4, xmiu, inp);

  k_ul1      <<<1360 + 3440, TPB, 0, stream>>>(inp, wn, x1, p1);
  k_logic2p  <<<dim3(85, 8, 2), TPB, 0, stream>>>(x1, p1, wn, p2);
  k_fin2     <<<cdiv(128*12*192, TPB), TPB, 0, stream>>>(p2, x2p);

  k_gemm<1536,1024,192,1,ACT_RELU><<<dim3(24,16,1), 256, 0, stream>>>(x2p, w1p, fc1_b, fc1h);
  k_gemm<1536,256,1024,8,ACT_NONE><<<dim3(24,4,8), 256, 0, stream>>>(fc1h, fc2_w, fc2_b, gp);
  k_tail     <<<1536, 256, 0, stream>>>(gp, fc2_b, fc3_w, fc3_b, out);
}